// Round 5
// baseline (847.059 us; speedup 1.0000x reference)
//
#include <hip/hip_runtime.h>
#include <hip/hip_cooperative_groups.h>
#include <cmath>

#define D_ 128
#define H_ 256
#define W4 64                         // 4-elem groups per row (256 wide)
#define PS (H_*W4)                    // plane stride in groups (16384)
#define NTOT (2*128*256*256)
#define GBLK 2048                     // fallback grid: b(2)*d(128)*h-eighth(8)
#define ROWS 8                        // fallback rows/thread
#define STOPF 1e-4f

typedef _Float16 h4 __attribute__((ext_vector_type(4)));
typedef _Float16 h2v __attribute__((ext_vector_type(2)));

__device__ __forceinline__ float lk(float x){ return x >= 0.f ? x : 0.01f*x; }
__device__ __forceinline__ float4 mn4(float4 a, float4 b){
    return make_float4(fminf(a.x,b.x),fminf(a.y,b.y),fminf(a.z,b.z),fminf(a.w,b.w)); }
__device__ __forceinline__ float4 ld4(const float4* p){ return *p; }
__device__ __forceinline__ float4 ld4(const h4* p){
    h4 v = *p; return make_float4((float)v.x,(float)v.y,(float)v.z,(float)v.w); }
__device__ __forceinline__ void st4(h4* p, float4 v){
    h4 r; r.x=(_Float16)v.x; r.y=(_Float16)v.y; r.z=(_Float16)v.z; r.w=(_Float16)v.w; *p = r; }
__device__ __forceinline__ float4 h4tof4(h4 v){
    return make_float4((float)v.x,(float)v.y,(float)v.z,(float)v.w); }
__device__ __forceinline__ h4 f4toh4(float4 v){
    h4 r; r.x=(_Float16)v.x; r.y=(_Float16)v.y; r.z=(_Float16)v.z; r.w=(_Float16)v.w; return r; }

// ---- packed fp16 helpers: v_pk_min/max_f16 (selection ops -> bit-exact) ----
#define PINF 0x7C007C00u
#define NINF 0xFC00FC00u
__device__ __forceinline__ uint32_t pmin(uint32_t a, uint32_t b){
    h2v r = __builtin_elementwise_min(__builtin_bit_cast(h2v,a), __builtin_bit_cast(h2v,b));
    return __builtin_bit_cast(uint32_t, r); }
__device__ __forceinline__ uint32_t pmax(uint32_t a, uint32_t b){
    h2v r = __builtin_elementwise_max(__builtin_bit_cast(h2v,a), __builtin_bit_cast(h2v,b));
    return __builtin_bit_cast(uint32_t, r); }
__device__ __forceinline__ uint2 pmin2(uint2 a, uint2 b){
    return make_uint2(pmin(a.x,b.x), pmin(a.y,b.y)); }
__device__ __forceinline__ uint2 pmax2(uint2 a, uint2 b){
    return make_uint2(pmax(a.x,b.x), pmax(a.y,b.y)); }
__device__ __forceinline__ float4 cvt4(uint32_t w01, uint32_t w23){
    h2v a = __builtin_bit_cast(h2v, w01);
    h2v b = __builtin_bit_cast(h2v, w23);
    return make_float4((float)a.x, (float)a.y, (float)b.x, (float)b.y); }

// ======================= fallback-path geometry (round-4, verified) =========
struct Geo { int lane, h0; size_t pbase; bool pm, pp; };
__device__ __forceinline__ Geo mkgeo(int tid, int bi){
    Geo g;
    g.lane = tid & 63;
    int wv = tid >> 6;
    int q = bi & 7, d = (bi >> 3) & 127, b = bi >> 10;
    g.h0 = q*32 + wv*ROWS;
    g.pbase = ((size_t)(b*128 + d))*PS + (size_t)g.lane;
    g.pm = (d > 0); g.pp = (d < 127);
    return g;
}

// ---- f32 core, p0 only (fp32 input erode) ----
__device__ __forceinline__ void phase_f32_erode(
    const float4* __restrict__ Xm, const float4* __restrict__ Xc, const float4* __restrict__ Xp,
    bool pm, bool pp, h4* __restrict__ Ep, int h0, int lane)
{
    const float INF = __builtin_inff();
    float4 dmn[3];
    auto ldrow = [&](int j){
        int s = j % 3; int h = h0 - 1 + j;
        if (h >= 0 && h < H_){
            float4 v = ld4(Xc + h*W4); float4 mn = v;
            if (pm){ mn = mn4(mn, ld4(Xm + h*W4)); }
            if (pp){ mn = mn4(mn, ld4(Xp + h*W4)); }
            dmn[s] = mn;
        } else dmn[s] = make_float4(INF,INF,INF,INF);
    };
    ldrow(0); ldrow(1);
#pragma unroll
    for (int r = 0; r < ROWS; ++r){
        ldrow(r+2);
        float4 vmn = mn4(dmn[0], mn4(dmn[1], dmn[2]));
        float lmn = __shfl_up(vmn.w,1);   if (lane == 0)  lmn = INF;
        float rmn = __shfl_down(vmn.x,1); if (lane == 63) rmn = INF;
        float4 e;
        e.x = fminf(lmn,  fminf(vmn.x,vmn.y));
        e.y = fminf(vmn.x,fminf(vmn.y,vmn.z));
        e.z = fminf(vmn.y,fminf(vmn.z,vmn.w));
        e.w = fminf(vmn.z,fminf(vmn.w,rmn));
        st4(Ep + (h0+r)*W4, e);
    }
}

// ---- fallback packed fp16 core (round-4, verified) ----
template<int MODE, typename CT>
__device__ __forceinline__ double phase_pk(
    const uint2* __restrict__ Xm, const uint2* __restrict__ Xc, const uint2* __restrict__ Xp,
    bool pm, bool pp,
    uint2* __restrict__ Ep, const CT* __restrict__ Cp, h4* __restrict__ Sp,
    float lr, int h0, int lane)
{
    uint2 rmn[4], rmx[4];
    double loc = 0.0;
    auto ldrow = [&](int j){
        int s = j & 3; int h = h0 - 1 + j;
        if (h >= 0 && h < H_){
            uint2 v = *(Xc + h*W4); uint2 mn = v, mx = v;
            if (pm){ uint2 u = *(Xm + h*W4); mn = pmin2(mn,u); mx = pmax2(mx,u); }
            if (pp){ uint2 u = *(Xp + h*W4); mn = pmin2(mn,u); mx = pmax2(mx,u); }
            rmn[s] = mn; rmx[s] = mx;
        } else {
            rmn[s] = make_uint2(PINF,PINF);
            rmx[s] = make_uint2(NINF,NINF);
        }
    };
    ldrow(0); ldrow(1); ldrow(2);
    float4 a_cur = ld4(Cp + h0*W4);
    float4 s_cur = make_float4(0,0,0,0);
    if constexpr(MODE >= 2) s_cur = ld4(Sp + h0*W4);
#pragma unroll
    for (int r = 0; r < ROWS; ++r){
        if (r + 3 <= ROWS + 1) ldrow(r+3);
        float4 a_nxt = a_cur, s_nxt = s_cur;
        if (r + 1 < ROWS){
            a_nxt = ld4(Cp + (h0+r+1)*W4);
            if constexpr(MODE >= 2) s_nxt = ld4(Sp + (h0+r+1)*W4);
        }
        uint2 vmn = pmin2(rmn[r&3], pmin2(rmn[(r+1)&3], rmn[(r+2)&3]));
        uint2 vmx = pmax2(rmx[r&3], pmax2(rmx[(r+1)&3], rmx[(r+2)&3]));
        uint32_t pwn = __shfl_up(vmn.y,1);   if (lane == 0)  pwn = PINF;
        uint32_t nwn = __shfl_down(vmn.x,1); if (lane == 63) nwn = PINF;
        uint32_t l01 = (pwn  >> 16) | (vmn.x << 16);
        uint32_t l23 = (vmn.x >> 16) | (vmn.y << 16);
        uint32_t r23 = (vmn.y >> 16) | (nwn  << 16);
        uint32_t e01 = pmin(pmin(l01, vmn.x), l23);
        uint32_t e23 = pmin(pmin(l23, vmn.y), r23);
        *(Ep + (h0+r)*W4) = make_uint2(e01, e23);
        uint32_t pwx = __shfl_up(vmx.y,1);   if (lane == 0)  pwx = NINF;
        uint32_t nwx = __shfl_down(vmx.x,1); if (lane == 63) nwx = NINF;
        uint32_t L01 = (pwx  >> 16) | (vmx.x << 16);
        uint32_t L23 = (vmx.x >> 16) | (vmx.y << 16);
        uint32_t R23 = (vmx.y >> 16) | (nwx  << 16);
        uint32_t o01 = pmax(pmax(L01, vmx.x), L23);
        uint32_t o23 = pmax(pmax(L23, vmx.y), R23);
        float4 o = cvt4(o01, o23);
        float4 a = a_cur;
        if constexpr(MODE == 1){
            float4 s0;
            s0.x = lk(a.x-o.x); s0.y = lk(a.y-o.y);
            s0.z = lk(a.z-o.z); s0.w = lk(a.w-o.w);
            st4(Sp + (h0+r)*W4, s0);
        } else {
            float4 s = s_cur;
            float4 up; float dl;
            dl = lk(a.x-o.x); up.x = lk(dl - s.x*dl)*lr; s.x += up.x;
            dl = lk(a.y-o.y); up.y = lk(dl - s.y*dl)*lr; s.y += up.y;
            dl = lk(a.z-o.z); up.z = lk(dl - s.z*dl)*lr; s.z += up.z;
            dl = lk(a.w-o.w); up.w = lk(dl - s.w*dl)*lr; s.w += up.w;
            st4(Sp + (h0+r)*W4, s);
            if constexpr(MODE == 2)
                loc += (double)(fabsf(s.x)+fabsf(s.y)+fabsf(s.z)+fabsf(s.w));
            else
                loc += (double)(fabsf(up.x)+fabsf(up.y)+fabsf(up.z)+fabsf(up.w));
        }
        a_cur = a_nxt; s_cur = s_nxt;
    }
    return loc;
}

// P0: R0 = erode(img0) (fp32 in, fp16 out); zero-inits frozen flag + norm slots.
__global__ __launch_bounds__(256) void p0_k(const float* __restrict__ img0,
                                            h4* __restrict__ R0,
                                            int* __restrict__ frozen,
                                            double* __restrict__ nrm){
    if (blockIdx.x == 0){
        if (threadIdx.x == 0) *frozen = 0;
        if (threadIdx.x < 320) nrm[threadIdx.x] = 0.0;
    }
    Geo g = mkgeo(threadIdx.x, blockIdx.x);
    const float4* Xc = (const float4*)img0 + g.pbase;
    phase_f32_erode(Xc-PS, Xc, Xc+PS, g.pm, g.pp, R0+g.pbase, g.h0, g.lane);
}

// ======================= cooperative persistent kernel ======================
// Grid 1024 = d(128) * b(2) * h-quarter(4), bi = d*8 + b*4 + q so each (b,q)
// slab (all d) lands on one XCD -> d-halo X reads are L2-local.
// Per wave: 16 rows. C lives in LDS (stashed X center rows from the previous
// phase -- C is read pointwise at own coords). S lives in registers as fp16
// (same rounding sequence as the HBM round-trip -> bit-identical numerics).
// Per-iteration fabric traffic: X-read + E-write only (~70 MB vs 167 MB).
template<int MODE>   // 1: p1-phase (C=img0 f32, init S). 2: iter0 (|S| norm). 3: |up| norm.
__device__ __forceinline__ double cphase(
    const uint2* __restrict__ Xm, const uint2* __restrict__ Xc, const uint2* __restrict__ Xp,
    bool pm, bool pp, uint2* __restrict__ Ep, const float4* __restrict__ C0,
    uint2* Clw, h4 (&S)[16], float lr, int h0, int lane)
{
    uint2 rmn[4], rmx[4], raw[3];
    double loc = 0.0;
    auto ldrow = [&](int j){
        int s = j & 3; int h = h0 - 1 + j;
        if (h >= 0 && h < H_){
            uint2 v = *(Xc + h*W4); uint2 mn = v, mx = v;
            if (j >= 1 && j <= 16) raw[(j-1)%3] = v;   // own rows only (always in range)
            if (pm){ uint2 u = *(Xm + h*W4); mn = pmin2(mn,u); mx = pmax2(mx,u); }
            if (pp){ uint2 u = *(Xp + h*W4); mn = pmin2(mn,u); mx = pmax2(mx,u); }
            rmn[s] = mn; rmx[s] = mx;
        } else {
            rmn[s] = make_uint2(PINF,PINF);
            rmx[s] = make_uint2(NINF,NINF);
        }
    };
    ldrow(0); ldrow(1); ldrow(2);
#pragma unroll
    for (int r = 0; r < 16; ++r){
        if (r + 3 <= 17) ldrow(r+3);
        uint2 vmn = pmin2(rmn[r&3], pmin2(rmn[(r+1)&3], rmn[(r+2)&3]));
        uint2 vmx = pmax2(rmx[r&3], pmax2(rmx[(r+1)&3], rmx[(r+2)&3]));
        uint32_t pwn = __shfl_up(vmn.y,1);   if (lane == 0)  pwn = PINF;
        uint32_t nwn = __shfl_down(vmn.x,1); if (lane == 63) nwn = PINF;
        uint32_t l01 = (pwn  >> 16) | (vmn.x << 16);
        uint32_t l23 = (vmn.x >> 16) | (vmn.y << 16);
        uint32_t r23 = (vmn.y >> 16) | (nwn  << 16);
        uint32_t e01 = pmin(pmin(l01, vmn.x), l23);
        uint32_t e23 = pmin(pmin(l23, vmn.y), r23);
        *(Ep + (h0+r)*W4) = make_uint2(e01, e23);
        uint32_t pwx = __shfl_up(vmx.y,1);   if (lane == 0)  pwx = NINF;
        uint32_t nwx = __shfl_down(vmx.x,1); if (lane == 63) nwx = NINF;
        uint32_t L01 = (pwx  >> 16) | (vmx.x << 16);
        uint32_t L23 = (vmx.x >> 16) | (vmx.y << 16);
        uint32_t R23 = (vmx.y >> 16) | (nwx  << 16);
        uint32_t o01 = pmax(pmax(L01, vmx.x), L23);
        uint32_t o23 = pmax(pmax(L23, vmx.y), R23);
        float4 o = cvt4(o01, o23);
        float4 a;
        if constexpr(MODE == 1) a = ld4(C0 + (h0+r)*W4);
        else { uint2 cw = Clw[r*64]; a = cvt4(cw.x, cw.y); }
        Clw[r*64] = raw[r%3];            // stash this iter's X center -> next iter's C
        if constexpr(MODE == 1){
            float4 s0;
            s0.x = lk(a.x-o.x); s0.y = lk(a.y-o.y);
            s0.z = lk(a.z-o.z); s0.w = lk(a.w-o.w);
            S[r] = f4toh4(s0);
        } else {
            float4 s = h4tof4(S[r]);
            float4 up; float dl;
            dl = lk(a.x-o.x); up.x = lk(dl - s.x*dl)*lr; s.x += up.x;
            dl = lk(a.y-o.y); up.y = lk(dl - s.y*dl)*lr; s.y += up.y;
            dl = lk(a.z-o.z); up.z = lk(dl - s.z*dl)*lr; s.z += up.z;
            dl = lk(a.w-o.w); up.w = lk(dl - s.w*dl)*lr; s.w += up.w;
            S[r] = f4toh4(s);
            if constexpr(MODE == 2)
                loc += (double)(fabsf(s.x)+fabsf(s.y)+fabsf(s.z)+fabsf(s.w));
            else
                loc += (double)(fabsf(up.x)+fabsf(up.y)+fabsf(up.z)+fabsf(up.w));
        }
    }
    return loc;
}

__global__ __launch_bounds__(256,4) void skel_k(const float* __restrict__ img0,
                                                h4* __restrict__ rg0,
                                                h4* __restrict__ rg1,
                                                h4* __restrict__ rg2,
                                                float* __restrict__ out,
                                                double* __restrict__ nrm){
    __shared__ uint2 Cl[64*64];          // 32 KB: block's C tile (64 rows x 256 w fp16)
    __shared__ double sm[5];
    cooperative_groups::grid_group gg = cooperative_groups::this_grid();
    int tid = threadIdx.x, lane = tid & 63, wv = tid >> 6;
    int bi = blockIdx.x;
    int d = bi >> 3, b = (bi >> 2) & 1, q = bi & 3;
    int h0 = q*64 + wv*16;
    size_t pbase = ((size_t)(b*128 + d))*PS + (size_t)lane;
    bool pm = d > 0, pp = d < 127;
    uint2* Clw = Cl + (wv*16)*64 + lane;
    h4 S[16];

    {   // p1-phase: X = R0, C = img0 (f32); S -> regs; stash R0 center rows
        const uint2* Xc = (const uint2*)rg0 + pbase;
        cphase<1>(Xc-PS, Xc, Xc+PS, pm, pp, (uint2*)rg1 + pbase,
                  (const float4*)img0 + pbase, Clw, S, 0.f, h0, lane);
    }
    gg.sync();

    for (int it = 0; it < 20; ++it){
        if (it > 0){
            if (tid == 0) sm[4] = *((volatile double*)(nrm + (size_t)(it-1)*16));
            __syncthreads();
            double tot = sm[4];
            if ((float)(tot / (double)NTOT) < STOPF) break;   // uniform across grid
        }
        int xs = (it+1)%3, es = (it+2)%3;
        h4* X = xs==0 ? rg0 : (xs==1 ? rg1 : rg2);
        h4* E = es==0 ? rg0 : (es==1 ? rg1 : rg2);
        float lr = 0.1f * exp2f(-(float)(it >> 2));
        const uint2* Xc = (const uint2*)X + pbase;
        uint2* Ep = (uint2*)E + pbase;
        double loc = (it == 0)
            ? cphase<2>(Xc-PS, Xc, Xc+PS, pm, pp, Ep, (const float4*)nullptr, Clw, S, lr, h0, lane)
            : cphase<3>(Xc-PS, Xc, Xc+PS, pm, pp, Ep, (const float4*)nullptr, Clw, S, lr, h0, lane);
#pragma unroll
        for (int o = 32; o; o >>= 1) loc += __shfl_down(loc, o);
        if (lane == 0) sm[wv] = loc;
        __syncthreads();
        if (tid == 0) atomicAdd(nrm + (size_t)it*16, sm[0]+sm[1]+sm[2]+sm[3]);
        gg.sync();   // E visible grid-wide; norm[it] complete; protects sm reuse
    }

    // dt == 0 identically -> out = 1.1 * S, straight from registers
    float4* O = (float4*)out + pbase;
#pragma unroll
    for (int r = 0; r < 16; ++r){
        float4 s = h4tof4(S[r]);
        O[(h0+r)*W4] = make_float4(1.1f*s.x, 1.1f*s.y, 1.1f*s.z, 1.1f*s.w);
    }
}

// ======================= fallback kernels (round-4, verified) ===============
__global__ __launch_bounds__(256) void p1_k(const h4* __restrict__ R0,
                                            const float* __restrict__ img0,
                                            h4* __restrict__ R1,
                                            h4* __restrict__ S){
    Geo g = mkgeo(threadIdx.x, blockIdx.x);
    const uint2* Xc = (const uint2*)R0 + g.pbase;
    phase_pk<1,float4>(Xc-PS, Xc, Xc+PS, g.pm, g.pp, (uint2*)R1 + g.pbase,
                       (const float4*)img0 + g.pbase, S + g.pbase, 0.f, g.h0, g.lane);
}

template<int MODE>
__global__ __launch_bounds__(256) void upd_k(const h4* __restrict__ Xb,
                                             const h4* __restrict__ Cb,
                                             h4* __restrict__ Eb,
                                             h4* __restrict__ Sb,
                                             const double* __restrict__ pr,
                                             double* __restrict__ pw,
                                             int* __restrict__ frozen,
                                             float lr){
    if (*frozen) return;
    __shared__ double sm[4];
    int tid = threadIdx.x;
    int lane = tid & 63, wv = tid >> 6;
    if constexpr(MODE == 3){
        double v = 0.0;
#pragma unroll
        for (int j = 0; j < GBLK/256; ++j) v += pr[tid + 256*j];
#pragma unroll
        for (int o = 32; o; o >>= 1) v += __shfl_down(v, o);
        if (lane == 0) sm[wv] = v;
        __syncthreads();
        double tot = sm[0] + sm[1] + sm[2] + sm[3];
        if ((float)(tot / (double)NTOT) < STOPF){
            if (tid == 0) *frozen = 1;
            return;
        }
        __syncthreads();
    }
    Geo g = mkgeo(tid, blockIdx.x);
    const uint2* Xc = (const uint2*)Xb + g.pbase;
    double loc = phase_pk<MODE,h4>(Xc-PS, Xc, Xc+PS, g.pm, g.pp,
                                   (uint2*)Eb + g.pbase, Cb + g.pbase, Sb + g.pbase,
                                   lr, g.h0, g.lane);
#pragma unroll
    for (int o = 32; o; o >>= 1) loc += __shfl_down(loc, o);
    if (lane == 0) sm[wv] = loc;
    __syncthreads();
    if (tid == 0) pw[blockIdx.x] = sm[0]+sm[1]+sm[2]+sm[3];
}

__global__ __launch_bounds__(256) void scale_k(const h4* __restrict__ S,
                                               float* __restrict__ out){
    int t = blockIdx.x*256 + threadIdx.x;
#pragma unroll
    for (int c = 0; c < 4; ++c){
        int i = t + c*1048576;
        float4 s = ld4(S + i);
        float4 r = make_float4(1.1f*s.x, 1.1f*s.y, 1.1f*s.z, 1.1f*s.w);
        *(float4*)(out + (size_t)i*4) = r;
    }
}

extern "C" void kernel_launch(void* const* d_in, const int* in_sizes, int n_in,
                              void* d_out, int out_size, void* d_ws, size_t ws_size,
                              hipStream_t stream){
    const float* img0 = (const float*)d_in[0];
    float* out = (float*)d_out;
    char* ws = (char*)d_ws;
    size_t volh = (size_t)NTOT * 2;            // fp16 volume: 33.5 MB
    h4* ring[3] = { (h4*)ws, (h4*)(ws + volh), (h4*)(ws + 2*volh) };
    h4* S       = (h4*)(ws + 3*volh);
    double* parts[2] = { (double*)(ws + 4*volh), (double*)(ws + 4*volh) + GBLK };
    int* frozen = (int*)(ws + 4*volh + 2*GBLK*sizeof(double));
    double* nrm = (double*)(ws + 4*volh + 2*GBLK*sizeof(double) + 128); // 128B-aligned

    dim3 blk(256);
    hipLaunchKernelGGL(p0_k, dim3(GBLK), blk, 0, stream, img0, ring[0], frozen, nrm);

    // cooperative persistent kernel: p1 + up to 20 iterations + final scale
    const float* a_img0 = img0;
    h4* a_r0 = ring[0]; h4* a_r1 = ring[1]; h4* a_r2 = ring[2];
    float* a_out = out; double* a_nrm = nrm;
    void* args[6] = { &a_img0, &a_r0, &a_r1, &a_r2, &a_out, &a_nrm };
    hipError_t ce = hipLaunchCooperativeKernel((const void*)skel_k, dim3(1024), blk,
                                               args, 0u, stream);
    if (ce != hipSuccess){
        // fallback: verified round-4 sequence (uses same p0 output + frozen/parts)
        hipLaunchKernelGGL(p1_k, dim3(GBLK), blk, 0, stream, ring[0], img0, ring[1], S);
        for (int i = 0; i < 20; ++i){
            h4* C = ring[i % 3];
            h4* X = ring[(i+1) % 3];
            h4* E = ring[(i+2) % 3];
            float lr = (float)(0.1 * pow(0.5, (double)(i / 4)));
            double* pw = parts[i & 1];
            double* pr = parts[1 - (i & 1)];
            if (i == 0)
                hipLaunchKernelGGL((upd_k<2>), dim3(GBLK), blk, 0, stream, X, C, E, S, pr, pw, frozen, lr);
            else
                hipLaunchKernelGGL((upd_k<3>), dim3(GBLK), blk, 0, stream, X, C, E, S, pr, pw, frozen, lr);
        }
        hipLaunchKernelGGL(scale_k, dim3(4096), blk, 0, stream, S, out);
    }
}

// Round 6
// 289.736 us; speedup vs baseline: 2.9236x; 2.9236x over previous
//
#include <hip/hip_runtime.h>
#include <hip/hip_cooperative_groups.h>
#include <cmath>

#define D_ 128
#define H_ 256
#define W4 64                         // 4-elem groups per row (256 wide)
#define PS (H_*W4)                    // plane stride in groups (16384)
#define NTOT (2*128*256*256)
#define GBLK 2048                     // upd grid: b(2)*d(128)*h-eighth(8)
#define ROWS 8                        // rows per thread (upd path)
#define TSTART 6                      // first iteration handled by coop tail
#define STOPF 1e-4f

typedef _Float16 h4 __attribute__((ext_vector_type(4)));
typedef _Float16 h2v __attribute__((ext_vector_type(2)));

__device__ __forceinline__ float lk(float x){ return x >= 0.f ? x : 0.01f*x; }
__device__ __forceinline__ float4 mn4(float4 a, float4 b){
    return make_float4(fminf(a.x,b.x),fminf(a.y,b.y),fminf(a.z,b.z),fminf(a.w,b.w)); }
__device__ __forceinline__ float4 ld4(const float4* p){ return *p; }
__device__ __forceinline__ float4 ld4(const h4* p){
    h4 v = *p; return make_float4((float)v.x,(float)v.y,(float)v.z,(float)v.w); }
__device__ __forceinline__ void st4(h4* p, float4 v){
    h4 r; r.x=(_Float16)v.x; r.y=(_Float16)v.y; r.z=(_Float16)v.z; r.w=(_Float16)v.w; *p = r; }
__device__ __forceinline__ float4 h4tof4(h4 v){
    return make_float4((float)v.x,(float)v.y,(float)v.z,(float)v.w); }

// ---- packed fp16 helpers: v_pk_min/max_f16 (selection ops -> bit-exact) ----
#define PINF 0x7C007C00u
#define NINF 0xFC00FC00u
__device__ __forceinline__ uint32_t pmin(uint32_t a, uint32_t b){
    h2v r = __builtin_elementwise_min(__builtin_bit_cast(h2v,a), __builtin_bit_cast(h2v,b));
    return __builtin_bit_cast(uint32_t, r); }
__device__ __forceinline__ uint32_t pmax(uint32_t a, uint32_t b){
    h2v r = __builtin_elementwise_max(__builtin_bit_cast(h2v,a), __builtin_bit_cast(h2v,b));
    return __builtin_bit_cast(uint32_t, r); }
__device__ __forceinline__ uint2 pmin2(uint2 a, uint2 b){
    return make_uint2(pmin(a.x,b.x), pmin(a.y,b.y)); }
__device__ __forceinline__ uint2 pmax2(uint2 a, uint2 b){
    return make_uint2(pmax(a.x,b.x), pmax(a.y,b.y)); }
__device__ __forceinline__ float4 cvt4(uint32_t w01, uint32_t w23){
    h2v a = __builtin_bit_cast(h2v, w01);
    h2v b = __builtin_bit_cast(h2v, w23);
    return make_float4((float)a.x, (float)a.y, (float)b.x, (float)b.y); }

// upd-path geometry: block bi covers (b, d, h-eighth); wave owns ROWS rows.
// h-eighth in LOW 3 bits -> d-neighbor blocks (share X planes) on same XCD.
struct Geo { int lane, h0; size_t pbase; bool pm, pp; };
__device__ __forceinline__ Geo mkgeo(int tid, int bi){
    Geo g;
    g.lane = tid & 63;
    int wv = tid >> 6;
    int q = bi & 7, d = (bi >> 3) & 127, b = bi >> 10;
    g.h0 = q*32 + wv*ROWS;
    g.pbase = ((size_t)(b*128 + d))*PS + (size_t)g.lane;
    g.pm = (d > 0); g.pp = (d < 127);
    return g;
}

// ---- f32 core, p0 only (fp32 input erode), 4-slot ring + distance-2 prefetch ----
__device__ __forceinline__ void phase_f32_erode(
    const float4* __restrict__ Xm, const float4* __restrict__ Xc, const float4* __restrict__ Xp,
    bool pm, bool pp, h4* __restrict__ Ep, int h0, int lane)
{
    const float INF = __builtin_inff();
    float4 dmn[4];
    auto ldrow = [&](int j){
        int s = j & 3; int h = h0 - 1 + j;
        if (h >= 0 && h < H_){
            float4 v = ld4(Xc + h*W4); float4 mn = v;
            if (pm){ mn = mn4(mn, ld4(Xm + h*W4)); }
            if (pp){ mn = mn4(mn, ld4(Xp + h*W4)); }
            dmn[s] = mn;
        } else dmn[s] = make_float4(INF,INF,INF,INF);
    };
    ldrow(0); ldrow(1); ldrow(2);
#pragma unroll
    for (int r = 0; r < ROWS; ++r){
        if (r + 3 <= ROWS + 1) ldrow(r+3);
        float4 vmn = mn4(dmn[r&3], mn4(dmn[(r+1)&3], dmn[(r+2)&3]));
        float lmn = __shfl_up(vmn.w,1);   if (lane == 0)  lmn = INF;
        float rmn = __shfl_down(vmn.x,1); if (lane == 63) rmn = INF;
        float4 e;
        e.x = fminf(lmn,  fminf(vmn.x,vmn.y));
        e.y = fminf(vmn.x,fminf(vmn.y,vmn.z));
        e.z = fminf(vmn.y,fminf(vmn.z,vmn.w));
        e.w = fminf(vmn.z,fminf(vmn.w,rmn));
        st4(Ep + (h0+r)*W4, e);
    }
}

// ---- packed fp16 core (p1 + update phases + tail), R rows/thread ----
// E = erode3(X) written out; O = dilate3(X) consumed inline (bit-exact packed
// morphology). S-update sequence identical to verified round-4 numerics.
// MODE 1: S = leaky(C - O). MODE 2: update, norm=|S_new|. MODE 3: update, norm=|up|.
template<int MODE, int R, typename CT>
__device__ __forceinline__ double phase_pk(
    const uint2* __restrict__ Xm, const uint2* __restrict__ Xc, const uint2* __restrict__ Xp,
    bool pm, bool pp,
    uint2* __restrict__ Ep, const CT* __restrict__ Cp, h4* __restrict__ Sp,
    float lr, int h0, int lane)
{
    uint2 rmn[4], rmx[4];
    double loc = 0.0;
    auto ldrow = [&](int j){
        int s = j & 3; int h = h0 - 1 + j;
        if (h >= 0 && h < H_){
            uint2 v = *(Xc + h*W4); uint2 mn = v, mx = v;
            if (pm){ uint2 u = *(Xm + h*W4); mn = pmin2(mn,u); mx = pmax2(mx,u); }
            if (pp){ uint2 u = *(Xp + h*W4); mn = pmin2(mn,u); mx = pmax2(mx,u); }
            rmn[s] = mn; rmx[s] = mx;
        } else {
            rmn[s] = make_uint2(PINF,PINF);
            rmx[s] = make_uint2(NINF,NINF);
        }
    };
    ldrow(0); ldrow(1); ldrow(2);
    float4 a_cur = ld4(Cp + h0*W4);
    float4 s_cur = make_float4(0,0,0,0);
    if constexpr(MODE >= 2) s_cur = ld4(Sp + h0*W4);
#pragma unroll
    for (int r = 0; r < R; ++r){
        if (r + 3 <= R + 1) ldrow(r+3);               // distance-2 prefetch
        float4 a_nxt = a_cur, s_nxt = s_cur;
        if (r + 1 < R){
            a_nxt = ld4(Cp + (h0+r+1)*W4);
            if constexpr(MODE >= 2) s_nxt = ld4(Sp + (h0+r+1)*W4);
        }
        uint2 vmn = pmin2(rmn[r&3], pmin2(rmn[(r+1)&3], rmn[(r+2)&3]));
        uint2 vmx = pmax2(rmx[r&3], pmax2(rmx[(r+1)&3], rmx[(r+2)&3]));
        uint32_t pwn = __shfl_up(vmn.y,1);   if (lane == 0)  pwn = PINF;
        uint32_t nwn = __shfl_down(vmn.x,1); if (lane == 63) nwn = PINF;
        uint32_t l01 = (pwn  >> 16) | (vmn.x << 16);
        uint32_t l23 = (vmn.x >> 16) | (vmn.y << 16);
        uint32_t r23 = (vmn.y >> 16) | (nwn  << 16);
        uint32_t e01 = pmin(pmin(l01, vmn.x), l23);
        uint32_t e23 = pmin(pmin(l23, vmn.y), r23);
        *(Ep + (h0+r)*W4) = make_uint2(e01, e23);
        uint32_t pwx = __shfl_up(vmx.y,1);   if (lane == 0)  pwx = NINF;
        uint32_t nwx = __shfl_down(vmx.x,1); if (lane == 63) nwx = NINF;
        uint32_t L01 = (pwx  >> 16) | (vmx.x << 16);
        uint32_t L23 = (vmx.x >> 16) | (vmx.y << 16);
        uint32_t R23 = (vmx.y >> 16) | (nwx  << 16);
        uint32_t o01 = pmax(pmax(L01, vmx.x), L23);
        uint32_t o23 = pmax(pmax(L23, vmx.y), R23);
        float4 o = cvt4(o01, o23);
        float4 a = a_cur;
        if constexpr(MODE == 1){
            float4 s0;
            s0.x = lk(a.x-o.x); s0.y = lk(a.y-o.y);
            s0.z = lk(a.z-o.z); s0.w = lk(a.w-o.w);
            st4(Sp + (h0+r)*W4, s0);
        } else {
            float4 s = s_cur;
            float4 up; float dl;
            dl = lk(a.x-o.x); up.x = lk(dl - s.x*dl)*lr; s.x += up.x;
            dl = lk(a.y-o.y); up.y = lk(dl - s.y*dl)*lr; s.y += up.y;
            dl = lk(a.z-o.z); up.z = lk(dl - s.z*dl)*lr; s.z += up.z;
            dl = lk(a.w-o.w); up.w = lk(dl - s.w*dl)*lr; s.w += up.w;
            st4(Sp + (h0+r)*W4, s);
            if constexpr(MODE == 2)
                loc += (double)(fabsf(s.x)+fabsf(s.y)+fabsf(s.z)+fabsf(s.w));
            else
                loc += (double)(fabsf(up.x)+fabsf(up.y)+fabsf(up.z)+fabsf(up.w));
        }
        a_cur = a_nxt; s_cur = s_nxt;
    }
    return loc;
}

// P0: R0 = erode(img0) (fp32 in, fp16 out); zero-inits frozen flag.
__global__ __launch_bounds__(256) void p0_k(const float* __restrict__ img0,
                                            h4* __restrict__ R0,
                                            int* __restrict__ frozen){
    if (blockIdx.x == 0 && threadIdx.x == 0) *frozen = 0;
    Geo g = mkgeo(threadIdx.x, blockIdx.x);
    const float4* Xc = (const float4*)img0 + g.pbase;
    phase_f32_erode(Xc-PS, Xc, Xc+PS, g.pm, g.pp, R0+g.pbase, g.h0, g.lane);
}

// P1: R1 = erode(R0); S = leaky(img0 - dilate(R0))
__global__ __launch_bounds__(256) void p1_k(const h4* __restrict__ R0,
                                            const float* __restrict__ img0,
                                            h4* __restrict__ R1,
                                            h4* __restrict__ S){
    Geo g = mkgeo(threadIdx.x, blockIdx.x);
    const uint2* Xc = (const uint2*)R0 + g.pbase;
    phase_pk<1,ROWS,float4>(Xc-PS, Xc, Xc+PS, g.pm, g.pp, (uint2*)R1 + g.pbase,
                            (const float4*)img0 + g.pbase, S + g.pbase, 0.f, g.h0, g.lane);
}

// Update phase i. On freeze detection: writes out = 1.1*S inline (grid covers
// the full volume; op order identical to scale_k -> bit-identical result).
template<int MODE>   // 2 (i==0, norm=|S|) or 3 (i>0, norm=|up|)
__global__ __launch_bounds__(256) void upd_k(const h4* __restrict__ Xb,
                                             const h4* __restrict__ Cb,
                                             h4* __restrict__ Eb,
                                             h4* __restrict__ Sb,
                                             const double* __restrict__ pr,
                                             double* __restrict__ pw,
                                             int* __restrict__ frozen,
                                             float* __restrict__ outp,
                                             float lr){
    if (*frozen) return;                       // cheap short-circuit after stop
    __shared__ double sm[4];
    int tid = threadIdx.x;
    int lane = tid & 63, wv = tid >> 6;
    if constexpr(MODE == 3){
        double v = 0.0;
#pragma unroll
        for (int j = 0; j < GBLK/256; ++j) v += pr[tid + 256*j];
#pragma unroll
        for (int o = 32; o; o >>= 1) v += __shfl_down(v, o);
        if (lane == 0) sm[wv] = v;
        __syncthreads();
        double tot = sm[0] + sm[1] + sm[2] + sm[3];
        if ((float)(tot / (double)NTOT) < STOPF){
            if (tid == 0) *frozen = 1;         // benign multi-block same-value write
            Geo g = mkgeo(tid, blockIdx.x);    // inline final scale: out = 1.1*S
            const h4* Sp = Sb + g.pbase;
            float4* O = (float4*)outp + g.pbase;
#pragma unroll
            for (int r = 0; r < ROWS; ++r){
                float4 s = h4tof4(Sp[(g.h0+r)*W4]);
                O[(g.h0+r)*W4] = make_float4(1.1f*s.x, 1.1f*s.y, 1.1f*s.z, 1.1f*s.w);
            }
            return;
        }
        __syncthreads();                       // protect sm reuse below
    }
    Geo g = mkgeo(tid, blockIdx.x);
    const uint2* Xc = (const uint2*)Xb + g.pbase;
    double loc = phase_pk<MODE,ROWS,h4>(Xc-PS, Xc, Xc+PS, g.pm, g.pp,
                                        (uint2*)Eb + g.pbase, Cb + g.pbase, Sb + g.pbase,
                                        lr, g.h0, g.lane);
#pragma unroll
    for (int o = 32; o; o >>= 1) loc += __shfl_down(loc, o);
    if (lane == 0) sm[wv] = loc;
    __syncthreads();
    if (tid == 0) pw[blockIdx.x] = sm[0]+sm[1]+sm[2]+sm[3];
}

// Cooperative tail: iterations TSTART..19 + finalize. Common case (already
// frozen -> scale done inline at freeze): read one flag and exit (~5 us),
// replacing 14 frozen launches + scale_k. Rare case: run remaining iterations
// with grid syncs (slow but correct), then scale.
__global__ __launch_bounds__(256) void tail_k(h4* __restrict__ rg0,
                                              h4* __restrict__ rg1,
                                              h4* __restrict__ rg2,
                                              h4* __restrict__ S,
                                              float* __restrict__ outp,
                                              const double* __restrict__ pr0,
                                              double* __restrict__ tp0,
                                              double* __restrict__ tp1,
                                              const int* __restrict__ frozen){
    if (*frozen) return;                       // scale already done at freeze
    cooperative_groups::grid_group gg = cooperative_groups::this_grid();
    __shared__ double sm[4];
    int tid = threadIdx.x, lane = tid & 63, wv = tid >> 6;
    int bi = blockIdx.x;
    int d = bi >> 3, b = (bi >> 2) & 1, q = bi & 3;   // 1024 blocks, 16 rows/thread
    int h0 = q*64 + wv*16;
    size_t pbase = ((size_t)(b*128 + d))*PS + (size_t)lane;
    bool pm = d > 0, pp = d < 127;
    const double* pr = pr0; int prn = GBLK;    // first check reads upd partials
    double* tpw = tp0;
    for (int i = TSTART; i < 20; ++i){
        double v = 0.0;
        for (int j = 0; j < prn/256; ++j) v += pr[tid + 256*j];
#pragma unroll
        for (int o = 32; o; o >>= 1) v += __shfl_down(v, o);
        if (lane == 0) sm[wv] = v;
        __syncthreads();
        double tot = sm[0] + sm[1] + sm[2] + sm[3];
        if ((float)(tot / (double)NTOT) < STOPF) break;   // uniform grid-wide
        __syncthreads();
        int xs = (i+1)%3, es = (i+2)%3, cs = i%3;
        h4* X = xs==0 ? rg0 : (xs==1 ? rg1 : rg2);
        h4* E = es==0 ? rg0 : (es==1 ? rg1 : rg2);
        h4* C = cs==0 ? rg0 : (cs==1 ? rg1 : rg2);
        float lr = 0.1f * exp2f(-(float)(i >> 2));
        const uint2* Xc = (const uint2*)X + pbase;
        double loc = phase_pk<3,16,h4>(Xc-PS, Xc, Xc+PS, pm, pp, (uint2*)E + pbase,
                                       C + pbase, S + pbase, lr, h0, lane);
#pragma unroll
        for (int o = 32; o; o >>= 1) loc += __shfl_down(loc, o);
        if (lane == 0) sm[wv] = loc;
        __syncthreads();
        if (tid == 0) tpw[blockIdx.x] = sm[0]+sm[1]+sm[2]+sm[3];
        gg.sync();                             // partials + E visible grid-wide
        pr = tpw; prn = 1024;
        tpw = (tpw == tp0) ? tp1 : tp0;
    }
    // finalize: out = 1.1*S over this block's slice (block-local S -> no sync)
    const h4* Sp = S + pbase;
    float4* O = (float4*)outp + pbase;
#pragma unroll
    for (int r = 0; r < 16; ++r){
        float4 s = h4tof4(Sp[(h0+r)*W4]);
        O[(h0+r)*W4] = make_float4(1.1f*s.x, 1.1f*s.y, 1.1f*s.z, 1.1f*s.w);
    }
}

// Fallback-only standalone scale (dt == 0 identically -> out = 1.1*S)
__global__ __launch_bounds__(256) void scale_k(const h4* __restrict__ S,
                                               float* __restrict__ out){
    int t = blockIdx.x*256 + threadIdx.x;
#pragma unroll
    for (int c = 0; c < 4; ++c){
        int i = t + c*1048576;
        float4 s = ld4(S + i);
        float4 r = make_float4(1.1f*s.x, 1.1f*s.y, 1.1f*s.z, 1.1f*s.w);
        *(float4*)(out + (size_t)i*4) = r;
    }
}

extern "C" void kernel_launch(void* const* d_in, const int* in_sizes, int n_in,
                              void* d_out, int out_size, void* d_ws, size_t ws_size,
                              hipStream_t stream){
    const float* img0 = (const float*)d_in[0];
    float* out = (float*)d_out;
    char* ws = (char*)d_ws;
    size_t volh = (size_t)NTOT * 2;            // fp16 volume: 33.5 MB
    h4* ring[3] = { (h4*)ws, (h4*)(ws + volh), (h4*)(ws + 2*volh) };
    h4* S       = (h4*)(ws + 3*volh);
    double* parts[2] = { (double*)(ws + 4*volh), (double*)(ws + 4*volh) + GBLK };
    int* frozen = (int*)(ws + 4*volh + 2*GBLK*sizeof(double));
    double* tp0 = (double*)(ws + 4*volh + 2*GBLK*sizeof(double) + 256);
    double* tp1 = tp0 + 1024;

    dim3 blk(256), grd(GBLK);
    hipLaunchKernelGGL(p0_k, grd, blk, 0, stream, img0, ring[0], frozen);
    hipLaunchKernelGGL(p1_k, grd, blk, 0, stream, ring[0], img0, ring[1], S);

    // iterations 0..TSTART-1 as plain dispatches (kernel boundary = cheap barrier)
    for (int i = 0; i < TSTART; ++i){
        h4* C = ring[i % 3];
        h4* X = ring[(i+1) % 3];
        h4* E = ring[(i+2) % 3];
        float lr = (float)(0.1 * pow(0.5, (double)(i / 4)));
        double* pw = parts[i & 1];
        double* pr = parts[1 - (i & 1)];
        if (i == 0)
            hipLaunchKernelGGL((upd_k<2>), grd, blk, 0, stream, X, C, E, S, pr, pw, frozen, out, lr);
        else
            hipLaunchKernelGGL((upd_k<3>), grd, blk, 0, stream, X, C, E, S, pr, pw, frozen, out, lr);
    }

    // coop tail: iterations TSTART..19 + finalize (fast exit when frozen)
    h4* a_r0 = ring[0]; h4* a_r1 = ring[1]; h4* a_r2 = ring[2];
    h4* a_S = S; float* a_out = out;
    const double* a_pr0 = parts[1 - (TSTART & 1)];   // partials written by i=TSTART-1
    double* a_tp0 = tp0; double* a_tp1 = tp1; int* a_fz = frozen;
    void* args[9] = { &a_r0, &a_r1, &a_r2, &a_S, &a_out, &a_pr0, &a_tp0, &a_tp1, &a_fz };
    hipError_t ce = hipLaunchCooperativeKernel((const void*)tail_k, dim3(1024), blk,
                                               args, 0u, stream);
    if (ce != hipSuccess){
        // fallback: verified round-4 sequence for the remaining iterations
        for (int i = TSTART; i < 20; ++i){
            h4* C = ring[i % 3];
            h4* X = ring[(i+1) % 3];
            h4* E = ring[(i+2) % 3];
            float lr = (float)(0.1 * pow(0.5, (double)(i / 4)));
            double* pw = parts[i & 1];
            double* pr = parts[1 - (i & 1)];
            hipLaunchKernelGGL((upd_k<3>), grd, blk, 0, stream, X, C, E, S, pr, pw, frozen, out, lr);
        }
        hipLaunchKernelGGL(scale_k, dim3(4096), blk, 0, stream, S, out);
    }
}